// Round 7
// baseline (1145.141 us; speedup 1.0000x reference)
//
#include <hip/hip_runtime.h>
#include <math.h>

typedef _Float16 f16;
typedef __attribute__((ext_vector_type(8))) _Float16 half8;
typedef __attribute__((ext_vector_type(4))) float float4v;

// ---------------- helpers ----------------
__device__ __forceinline__ float fast_sigmoid(float x) { return 1.0f / (1.0f + __expf(-x)); }
__device__ __forceinline__ float fast_tanh(float x) {
    float a = fabsf(x);
    float e = __expf(-2.0f * a);
    float t = (1.0f - e) / (1.0f + e);
    return copysignf(t, x);
}

// async global->LDS, 16B per lane (64 lanes = 1KB per instruction).
// LDS dest = wave-uniform base + lane*16; global src is per-lane.
__device__ __forceinline__ void async_copy16(const void* gsrc, void* ldst) {
    __builtin_amdgcn_global_load_lds(
        (const __attribute__((address_space(1))) void*)gsrc,
        (__attribute__((address_space(3))) void*)ldst,
        16, 0, 0);
}

// ---------------- prep kernels ----------------
// kt-major, LDS-image B pack: Bpk[cb][kt][colp][sj][e] (f16), 16KB per (cb,kt).
// Element = W[col'][ kt*32 + ((sj ^ ((colp>>1)&3))<<3) + e ], col' = cb*256+colp
// (gate-permuted col' -> j). Staging reads contiguous 1KB bursts.
__global__ void packb_kernel(const float* __restrict__ Wih, int Kih,
                             const float* __restrict__ Whh, int K, int NKT,
                             const float* __restrict__ bih, const float* __restrict__ bhh,
                             f16* __restrict__ Bpk, float* __restrict__ bp) {
    int t = blockIdx.x * blockDim.x + threadIdx.x;
    if (t >= (K << 9)) return;        // 512*K elements total
    int e = t & 7;
    int sj = (t >> 3) & 3;
    int colp = (t >> 5) & 255;
    int rest = t >> 13;
    int kt = rest % NKT;
    int cb = rest / NKT;
    int swz = (colp >> 1) & 3;
    int k = kt * 32 + ((sj ^ swz) << 3) + e;
    int colq = cb * 256 + colp;
    int dg = colq >> 6, q = (colq >> 4) & 3, dl = colq & 15;
    int j = q * 128 + dg * 16 + dl;
    float v = (k < Kih) ? Wih[j * Kih + k] : Whh[j * (K - Kih) + (k - Kih)];
    Bpk[t] = (f16)v;
    if (kt == 0 && e == 0 && sj == swz) bp[colq] = bih[j] + bhh[j];
}

__global__ void feat0_kernel(const float* __restrict__ features, const float* __restrict__ W_in,
                             const float* __restrict__ b_in, f16* __restrict__ feat, int n) {
    int t = blockIdx.x * blockDim.x + threadIdx.x;
    if (t >= n * 128) return;
    int node = t >> 7;
    int d = t & 127;
    float s = b_in[d];
#pragma unroll
    for (int k = 0; k < 6; ++k) s += features[node * 6 + k] * W_in[k * 128 + d];
    feat[t] = (f16)fmaxf(s, 0.0f);
}

__global__ void hist_kernel(const int* __restrict__ dst, int* __restrict__ cnt, int e) {
    int t = blockIdx.x * blockDim.x + threadIdx.x;
    if (t < e) atomicAdd(&cnt[dst[t]], 1);
}

// single-block scan, coalesced
__global__ void scan_kernel(const int* __restrict__ cnt, int* __restrict__ off,
                            int* __restrict__ cur, float* __restrict__ recip, int n) {
    __shared__ int wsum[16];
    __shared__ int stot;
    int t = threadIdx.x;       // 1024
    int lane = t & 63, wv = t >> 6;
    int R = 0;
    int rounds = (n + 1023) >> 10;
    for (int i = 0; i < rounds; ++i) {
        int idx = (i << 10) + t;
        int v = (idx < n) ? cnt[idx] : 0;
        int s = v;
#pragma unroll
        for (int o = 1; o < 64; o <<= 1) {
            int u = __shfl_up(s, o, 64);
            if (lane >= o) s += u;
        }
        if (lane == 63) wsum[wv] = s;
        __syncthreads();
        if (t == 0) {
            int a = 0;
#pragma unroll
            for (int j = 0; j < 16; ++j) { int x = wsum[j]; wsum[j] = a; a += x; }
            stot = a;
        }
        __syncthreads();
        int excl = R + wsum[wv] + s - v;
        if (idx < n) {
            off[idx] = excl; cur[idx] = excl;
            recip[idx] = (v > 0) ? 1.0f / (float)v : 0.0f;
        }
        R += stot;
        __syncthreads();
    }
    if (t == 0) off[n] = R;
}

__global__ void scatter_kernel(const int* __restrict__ src, const int* __restrict__ dst,
                               int* __restrict__ cur, int* __restrict__ esrc, int e) {
    int t = blockIdx.x * blockDim.x + threadIdx.x;
    if (t >= e) return;
    int d = dst[t];
    int p = atomicAdd(&cur[d], 1);
    esrc[p] = src[t];
}

// mean aggregation: 16 lanes (8 halves each) per node, 16 nodes/block (proven)
__global__ __launch_bounds__(256, 6) void agg_kernel(
    const f16* __restrict__ feat, const int* __restrict__ off,
    const int* __restrict__ esrc, const float* __restrict__ recip,
    f16* __restrict__ agg, int n) {
    int slot = threadIdx.x >> 4;
    int lane = threadIdx.x & 15;
    int v = blockIdx.x * 16 + slot;
    if (v >= n) return;
    int e0 = off[v], e1 = off[v + 1];
    float a[8];
#pragma unroll
    for (int j = 0; j < 8; ++j) a[j] = 0.0f;
    int e = e0;
    for (; e + 8 <= e1; e += 8) {
        int ss[8];
#pragma unroll
        for (int u = 0; u < 8; ++u) ss[u] = esrc[e + u];
        half8 vv[8];
#pragma unroll
        for (int u = 0; u < 8; ++u)
            vv[u] = *(const half8*)&feat[(size_t)ss[u] * 128 + lane * 8];
#pragma unroll
        for (int u = 0; u < 8; ++u)
#pragma unroll
            for (int j = 0; j < 8; ++j) a[j] += (float)vv[u][j];
    }
    for (; e < e1; ++e) {
        int s = esrc[e];
        half8 v0 = *(const half8*)&feat[(size_t)s * 128 + lane * 8];
#pragma unroll
        for (int j = 0; j < 8; ++j) a[j] += (float)v0[j];
    }
    float r = recip[v];
    half8 o;
#pragma unroll
    for (int j = 0; j < 8; ++j) o[j] = (f16)(a[j] * r);
    *(half8*)&agg[(size_t)v * 128 + lane * 8] = o;
}

// ---------------- fused MFMA GEMM + LSTM cell ----------------
// Round-6 proven machinery; BM 64 -> 128 to halve the dominant B-tile L2
// re-read traffic (B bytes per dispatch scale as 1/BM). Tile 128x256, wave =
// 128 rows x 64 cols = 8x4 MFMA grid. acc = 128 VGPR -> launch_bounds(256,2),
// 2 blocks/CU (LDS 48KB). Barrier-drain events also halve (blocks x NT).
// FIRST=true: skip all-zero h-state A-part at step 0 and the c_old read.
#define BM 128

template <int PARTS, bool FIRST>
__global__ __launch_bounds__(256, 2) void gemm_lstm(
    const f16* __restrict__ A0, const f16* __restrict__ A1, const f16* __restrict__ A2,
    const f16* __restrict__ Bpk, const float* __restrict__ bp,
    float* __restrict__ c, f16* __restrict__ h_out, int nrows) {
    constexpr int NKT = PARTS * 4;                           // B chunks in pack
    constexpr int NT = FIRST ? (PARTS - 1) * 4 : PARTS * 4;  // kt actually run
    __shared__ f16 As[2][128 * 32];   // 16 KB
    __shared__ f16 Bs[2][256 * 32];   // 32 KB

    const int tid = threadIdx.x;
    const int w = tid >> 6;      // wave 0..3 (col-wave)
    const int lane = tid & 63;
    const int dl = lane & 15;
    const int quad = lane >> 4;
    const int row0 = blockIdx.x * BM;
    const int cb = blockIdx.y;   // 0..1

    float4v acc[8][4];  // [row-tile rt][gate q]
#pragma unroll
    for (int q = 0; q < 4; ++q) {
        float b = bp[cb * 256 + w * 64 + q * 16 + dl];
#pragma unroll
        for (int rt = 0; rt < 8; ++rt) {
            acc[rt][q][0] = b; acc[rt][q][1] = b; acc[rt][q][2] = b; acc[rt][q][3] = b;
        }
    }

    const int srow = lane >> 2;       // A staging row within 16-row group
    const int sj = lane & 3;          // A staging slot
    const int sg = sj ^ ((srow >> 1) & 3);            // swizzled global k-group
    const int rslot = (quad ^ ((dl >> 1) & 3)) << 3;  // swizzled read slot (halves)

    // per-lane source base into the kt-major pack (this wave's 4KB share)
    const f16* Bk0 = Bpk + (size_t)cb * NKT * 8192 + w * 2048 + lane * 8;

    auto stage = [&](int kt, int bsel) {
        const f16* Ap = A0;
        const int pi = kt >> 2;
        if (PARTS >= 2 && pi == 1) Ap = A1;
        if (PARTS >= 3 && pi == 2) Ap = A2;
        const int kk = (kt & 3) * 32;   // A-part-local k offset
        // A: wave w stages rows w*32 .. w*32+31 (2 x 1KB = 2 x 16 rows)
#pragma unroll
        for (int i = 0; i < 2; ++i)
            async_copy16(&Ap[(size_t)(row0 + w * 32 + i * 16 + srow) * 128 + kk + (sg << 3)],
                         (f16*)As[bsel] + w * 1024 + i * 512);
        // B: 4 x contiguous 1KB bursts per wave from the kt-major LDS-image pack
        const f16* Bsrc = Bk0 + (size_t)kt * 8192;
#pragma unroll
        for (int i = 0; i < 4; ++i)
            async_copy16(Bsrc + i * 512, (f16*)Bs[bsel] + w * 2048 + i * 512);
    };

    // prologue: stage tile 0; __syncthreads drains vmcnt(0) for all threads
    stage(0, 0);
    __syncthreads();

    for (int kt = 0; kt < NT; ++kt) {
        const int cur = kt & 1;
        if (kt + 1 < NT) stage(kt + 1, cur ^ 1);   // prefetch overlaps compute

        half8 a[8], b[4];
#pragma unroll
        for (int rt = 0; rt < 8; ++rt)
            a[rt] = *(const half8*)&As[cur][(rt * 16 + dl) * 32 + rslot];
#pragma unroll
        for (int q = 0; q < 4; ++q)
            b[q] = *(const half8*)&Bs[cur][((w * 4 + q) * 16 + dl) * 32 + rslot];
#pragma unroll
        for (int rt = 0; rt < 8; ++rt)
#pragma unroll
            for (int q = 0; q < 4; ++q)
                acc[rt][q] = __builtin_amdgcn_mfma_f32_16x16x32_f16(a[rt], b[q], acc[rt][q], 0, 0, 0);

        __syncthreads();   // drains vmcnt(0)+lgkmcnt(0): prefetch visible, reads done
    }

    // epilogue: lane owns dim d, rows rt*16 + quad*4 + r, gates in acc[rt][*]
    // c in block-private coalesced layout: 32 KB per (row-block, col-half)
    float* cpriv = c + ((size_t)(blockIdx.x * 2 + cb)) * 8192;
    const int d = cb * 64 + w * 16 + dl;
#pragma unroll
    for (int rt = 0; rt < 8; ++rt) {
        float4v ig = acc[rt][0], fg = acc[rt][1], gg = acc[rt][2], og = acc[rt][3];
        float* cp = cpriv + rt * 1024 + tid * 4;
        float4v cold;
        if (FIRST) {
            cold[0] = 0.0f; cold[1] = 0.0f; cold[2] = 0.0f; cold[3] = 0.0f;
        } else {
            cold = *(const float4v*)cp;
        }
        float4v cn;
        float hn[4];
#pragma unroll
        for (int r = 0; r < 4; ++r) {
            float i_ = fast_sigmoid(ig[r]);
            float f_ = fast_sigmoid(fg[r]);
            float g_ = fast_tanh(gg[r]);
            float o_ = fast_sigmoid(og[r]);
            float cv = f_ * cold[r] + i_ * g_;
            cn[r] = cv;
            hn[r] = o_ * fast_tanh(cv);
        }
        *(float4v*)cp = cn;
#pragma unroll
        for (int r = 0; r < 4; ++r) {
            int nr = row0 + rt * 16 + (quad << 2) + r;
            if (nr < nrows) h_out[(size_t)nr * 128 + d] = (f16)hn[r];
        }
    }
}

// ---------------- output projection: 16 nodes/block ----------------
__global__ __launch_bounds__(256, 8) void out_kernel(
    const f16* __restrict__ h2, const float* __restrict__ Wout,
    const float* __restrict__ bout, float* __restrict__ out, int n) {
    int grp = threadIdx.x >> 4;
    int l = threadIdx.x & 15;
    int node = blockIdx.x * 16 + grp;
    if (node >= n) return;
    half8 h = *(const half8*)&h2[(size_t)node * 128 + l * 8];
    float s = 0.0f;
#pragma unroll
    for (int j = 0; j < 8; ++j) s += (float)h[j] * Wout[l * 8 + j];
#pragma unroll
    for (int o = 8; o > 0; o >>= 1) s += __shfl_down(s, o, 16);
    if (l == 0) out[node] = s + bout[0];
}

// ---------------- launch ----------------
extern "C" void kernel_launch(void* const* d_in, const int* in_sizes, int n_in,
                              void* d_out, int out_size, void* d_ws, size_t ws_size,
                              hipStream_t stream) {
    const float* features = (const float*)d_in[0];
    const int*   src      = (const int*)d_in[1];
    const int*   dst      = (const int*)d_in[2];
    const float* W_in     = (const float*)d_in[3];
    const float* b_in     = (const float*)d_in[4];
    const float* Wih0     = (const float*)d_in[5];
    const float* Wih_rest = (const float*)d_in[6];
    const float* Whh      = (const float*)d_in[7];
    const float* bih      = (const float*)d_in[8];
    const float* bhh      = (const float*)d_in[9];
    const float* W_out    = (const float*)d_in[10];
    const float* b_out    = (const float*)d_in[11];
    float* out = (float*)d_out;

    const int N = in_sizes[0] / 6;  // 20000
    const int E = in_sizes[1];      // 640000
    const int NP = N + BM;          // padded rows: staging never reads unmapped mem
    const int NBX = (N + BM - 1) / BM;   // 157

    char* ws = (char*)d_ws;
    size_t pos = 0;
    auto alloc = [&](size_t bytes) -> void* {
        void* p = ws + pos;
        pos = (pos + bytes + 255) & ~(size_t)255;
        return p;
    };
    const size_t hrow = 128;
    const size_t hbytes = (size_t)NP * hrow * sizeof(f16);
    const size_t cbytes = (size_t)NP * hrow * sizeof(float);
    f16* feath = (f16*)alloc(hbytes);
    f16* aggh  = (f16*)alloc(hbytes);
    f16* hblk  = (f16*)alloc(6 * hbytes);   // ping-pong: A-set then B-set
    f16* hA[3], * hB[3];
    for (int l = 0; l < 3; ++l) {
        hA[l] = hblk + (size_t)l * NP * hrow;
        hB[l] = hblk + (size_t)(l + 3) * NP * hrow;
    }
    float* cblk = (float*)alloc(3 * cbytes);
    float* c0 = cblk + 0 * (size_t)NP * hrow;   // block-private layout, 157*2*8192 <= NP*128
    float* c1 = cblk + 1 * (size_t)NP * hrow;
    float* c2 = cblk + 2 * (size_t)NP * hrow;
    f16* Bp0 = (f16*)alloc((size_t)512 * 384 * sizeof(f16));
    f16* Bp1 = (f16*)alloc((size_t)512 * 256 * sizeof(f16));
    f16* Bp2 = (f16*)alloc((size_t)512 * 256 * sizeof(f16));
    float* bp0 = (float*)alloc(512 * sizeof(float));
    float* bp1 = (float*)alloc(512 * sizeof(float));
    float* bp2 = (float*)alloc(512 * sizeof(float));
    int*   cnt   = (int*)alloc((size_t)N * 4);
    int*   offs  = (int*)alloc((size_t)(N + 1) * 4);
    int*   cur   = (int*)alloc((size_t)N * 4);
    int*   esrc  = (int*)alloc((size_t)E * 4);
    float* recip = (float*)alloc((size_t)N * 4);

    hipMemsetAsync(cnt, 0, (size_t)N * 4, stream);
    hipMemsetAsync(feath + (size_t)N * hrow, 0, (size_t)(NP - N) * hrow * sizeof(f16), stream);
    hipMemsetAsync(aggh + (size_t)N * hrow, 0, (size_t)(NP - N) * hrow * sizeof(f16), stream);

    // kt-major packs: L0 NKT=12, L1/L2 NKT=8
    packb_kernel<<<(512 * 384 + 255) / 256, 256, 0, stream>>>(
        Wih0, 256, Whh, 384, 12, bih, bhh, Bp0, bp0);
    packb_kernel<<<(512 * 256 + 255) / 256, 256, 0, stream>>>(
        Wih_rest, 128, Whh + 512 * 128, 256, 8, bih + 512, bhh + 512, Bp1, bp1);
    packb_kernel<<<(512 * 256 + 255) / 256, 256, 0, stream>>>(
        Wih_rest + 512 * 128, 128, Whh + 2 * 512 * 128, 256, 8, bih + 1024, bhh + 1024, Bp2, bp2);

    feat0_kernel<<<(N * 128 + 255) / 256, 256, 0, stream>>>(features, W_in, b_in, feath, N);
    hist_kernel<<<(E + 255) / 256, 256, 0, stream>>>(dst, cnt, E);
    scan_kernel<<<1, 1024, 0, stream>>>(cnt, offs, cur, recip, N);
    scatter_kernel<<<(E + 255) / 256, 256, 0, stream>>>(src, dst, cur, esrc, E);

    const dim3 ggrid(NBX, 2, 1);
    const int gagg = (N + 15) / 16;
    const f16* featcur = feath;
    f16 *r0 = hA[0], *r1 = hA[1], *r2 = hA[2];   // read (old state)
    f16 *w0 = hB[0], *w1 = hB[1], *w2 = hB[2];   // write (new state)
    for (int step = 0; step < 11; ++step) {
        agg_kernel<<<gagg, 256, 0, stream>>>(featcur, offs, esrc, recip, aggh, N);
        if (step == 0) {
            gemm_lstm<3, true ><<<ggrid, 256, 0, stream>>>(aggh, featcur, r0, Bp0, bp0, c0, w0, N);
            gemm_lstm<2, true ><<<ggrid, 256, 0, stream>>>(w0, r1, nullptr, Bp1, bp1, c1, w1, N);
            gemm_lstm<2, true ><<<ggrid, 256, 0, stream>>>(w1, r2, nullptr, Bp2, bp2, c2, w2, N);
        } else {
            gemm_lstm<3, false><<<ggrid, 256, 0, stream>>>(aggh, featcur, r0, Bp0, bp0, c0, w0, N);
            gemm_lstm<2, false><<<ggrid, 256, 0, stream>>>(w0, r1, nullptr, Bp1, bp1, c1, w1, N);
            gemm_lstm<2, false><<<ggrid, 256, 0, stream>>>(w1, r2, nullptr, Bp2, bp2, c2, w2, N);
        }
        featcur = w2;
        f16* t;
        t = r0; r0 = w0; w0 = t;
        t = r1; r1 = w1; w1 = t;
        t = r2; r2 = w2; w2 = t;
    }
    out_kernel<<<(N + 15) / 16, 256, 0, stream>>>((const f16*)featcur, W_out, b_out, out, N);
}

// Round 8
// 1094.314 us; speedup vs baseline: 1.0464x; 1.0464x over previous
//
#include <hip/hip_runtime.h>
#include <math.h>

typedef _Float16 f16;
typedef __attribute__((ext_vector_type(8))) _Float16 half8;
typedef __attribute__((ext_vector_type(4))) float float4v;

// ---------------- helpers ----------------
__device__ __forceinline__ float fast_sigmoid(float x) { return 1.0f / (1.0f + __expf(-x)); }
__device__ __forceinline__ float fast_tanh(float x) {
    float a = fabsf(x);
    float e = __expf(-2.0f * a);
    float t = (1.0f - e) / (1.0f + e);
    return copysignf(t, x);
}

// async global->LDS, 16B per lane (64 lanes = 1KB per instruction).
// LDS dest = wave-uniform base + lane*16; global src is per-lane.
__device__ __forceinline__ void async_copy16(const void* gsrc, void* ldst) {
    __builtin_amdgcn_global_load_lds(
        (const __attribute__((address_space(1))) void*)gsrc,
        (__attribute__((address_space(3))) void*)ldst,
        16, 0, 0);
}

// ---------------- prep kernels ----------------
// kt-major, LDS-image B pack: Bpk[cb][kt][colp][sj][e] (f16), 16KB per (cb,kt).
// Element = W[col'][ kt*32 + ((sj ^ ((colp>>1)&3))<<3) + e ], col' = cb*256+colp
// (gate-permuted col' -> j). Staging reads contiguous 1KB bursts.
__global__ void packb_kernel(const float* __restrict__ Wih, int Kih,
                             const float* __restrict__ Whh, int K, int NKT,
                             const float* __restrict__ bih, const float* __restrict__ bhh,
                             f16* __restrict__ Bpk, float* __restrict__ bp) {
    int t = blockIdx.x * blockDim.x + threadIdx.x;
    if (t >= (K << 9)) return;        // 512*K elements total
    int e = t & 7;
    int sj = (t >> 3) & 3;
    int colp = (t >> 5) & 255;
    int rest = t >> 13;
    int kt = rest % NKT;
    int cb = rest / NKT;
    int swz = (colp >> 1) & 3;
    int k = kt * 32 + ((sj ^ swz) << 3) + e;
    int colq = cb * 256 + colp;
    int dg = colq >> 6, q = (colq >> 4) & 3, dl = colq & 15;
    int j = q * 128 + dg * 16 + dl;
    float v = (k < Kih) ? Wih[j * Kih + k] : Whh[j * (K - Kih) + (k - Kih)];
    Bpk[t] = (f16)v;
    if (kt == 0 && e == 0 && sj == swz) bp[colq] = bih[j] + bhh[j];
}

__global__ void feat0_kernel(const float* __restrict__ features, const float* __restrict__ W_in,
                             const float* __restrict__ b_in, f16* __restrict__ feat, int n) {
    int t = blockIdx.x * blockDim.x + threadIdx.x;
    if (t >= n * 128) return;
    int node = t >> 7;
    int d = t & 127;
    float s = b_in[d];
#pragma unroll
    for (int k = 0; k < 6; ++k) s += features[node * 6 + k] * W_in[k * 128 + d];
    feat[t] = (f16)fmaxf(s, 0.0f);
}

__global__ void hist_kernel(const int* __restrict__ dst, int* __restrict__ cnt, int e) {
    int t = blockIdx.x * blockDim.x + threadIdx.x;
    if (t < e) atomicAdd(&cnt[dst[t]], 1);
}

// single-block scan, coalesced
__global__ void scan_kernel(const int* __restrict__ cnt, int* __restrict__ off,
                            int* __restrict__ cur, float* __restrict__ recip, int n) {
    __shared__ int wsum[16];
    __shared__ int stot;
    int t = threadIdx.x;       // 1024
    int lane = t & 63, wv = t >> 6;
    int R = 0;
    int rounds = (n + 1023) >> 10;
    for (int i = 0; i < rounds; ++i) {
        int idx = (i << 10) + t;
        int v = (idx < n) ? cnt[idx] : 0;
        int s = v;
#pragma unroll
        for (int o = 1; o < 64; o <<= 1) {
            int u = __shfl_up(s, o, 64);
            if (lane >= o) s += u;
        }
        if (lane == 63) wsum[wv] = s;
        __syncthreads();
        if (t == 0) {
            int a = 0;
#pragma unroll
            for (int j = 0; j < 16; ++j) { int x = wsum[j]; wsum[j] = a; a += x; }
            stot = a;
        }
        __syncthreads();
        int excl = R + wsum[wv] + s - v;
        if (idx < n) {
            off[idx] = excl; cur[idx] = excl;
            recip[idx] = (v > 0) ? 1.0f / (float)v : 0.0f;
        }
        R += stot;
        __syncthreads();
    }
    if (t == 0) off[n] = R;
}

__global__ void scatter_kernel(const int* __restrict__ src, const int* __restrict__ dst,
                               int* __restrict__ cur, int* __restrict__ esrc, int e) {
    int t = blockIdx.x * blockDim.x + threadIdx.x;
    if (t >= e) return;
    int d = dst[t];
    int p = atomicAdd(&cur[d], 1);
    esrc[p] = src[t];
}

// ---- degree-sort permutation (counting sort, 128 bins, degree clamped) ----
__global__ void dhist_kernel(const int* __restrict__ cnt, int* __restrict__ dh, int n) {
    int t = blockIdx.x * blockDim.x + threadIdx.x;
    if (t < n) atomicAdd(&dh[min(cnt[t], 127)], 1);
}

__global__ void dscan_kernel(const int* __restrict__ dh, int* __restrict__ dcur) {
    int t = threadIdx.x;       // 128
    int lane = t & 63, wv = t >> 6;
    __shared__ int w0sum;
    int v = dh[t];
    int s = v;
#pragma unroll
    for (int o = 1; o < 64; o <<= 1) {
        int u = __shfl_up(s, o, 64);
        if (lane >= o) s += u;
    }
    if (t == 63) w0sum = s;
    __syncthreads();
    dcur[t] = s - v + (wv ? w0sum : 0);
}

__global__ void dperm_kernel(const int* __restrict__ cnt, int* __restrict__ dcur,
                             int* __restrict__ perm, int n) {
    int t = blockIdx.x * blockDim.x + threadIdx.x;
    if (t >= n) return;
    int p = atomicAdd(&dcur[min(cnt[t], 127)], 1);
    perm[p] = t;
}

// mean aggregation: 16 lanes (8 halves each) per node, 16 nodes/block.
// Nodes processed in degree-sorted order (perm) so each wave's 4 nodes have
// ~equal edge counts -> no exec-masked idle tail (Poisson max-of-4 ~ +18%).
__global__ __launch_bounds__(256, 6) void agg_kernel(
    const f16* __restrict__ feat, const int* __restrict__ off,
    const int* __restrict__ esrc, const float* __restrict__ recip,
    const int* __restrict__ perm,
    f16* __restrict__ agg, int n) {
    int slot = threadIdx.x >> 4;
    int lane = threadIdx.x & 15;
    int idx = blockIdx.x * 16 + slot;
    if (idx >= n) return;
    int v = perm[idx];
    int e0 = off[v], e1 = off[v + 1];
    float a[8];
#pragma unroll
    for (int j = 0; j < 8; ++j) a[j] = 0.0f;
    int e = e0;
    for (; e + 8 <= e1; e += 8) {
        int ss[8];
#pragma unroll
        for (int u = 0; u < 8; ++u) ss[u] = esrc[e + u];
        half8 vv[8];
#pragma unroll
        for (int u = 0; u < 8; ++u)
            vv[u] = *(const half8*)&feat[(size_t)ss[u] * 128 + lane * 8];
#pragma unroll
        for (int u = 0; u < 8; ++u)
#pragma unroll
            for (int j = 0; j < 8; ++j) a[j] += (float)vv[u][j];
    }
    for (; e < e1; ++e) {
        int s = esrc[e];
        half8 v0 = *(const half8*)&feat[(size_t)s * 128 + lane * 8];
#pragma unroll
        for (int j = 0; j < 8; ++j) a[j] += (float)v0[j];
    }
    float r = recip[v];
    half8 o;
#pragma unroll
    for (int j = 0; j < 8; ++j) o[j] = (f16)(a[j] * r);
    *(half8*)&agg[(size_t)v * 128 + lane * 8] = o;
}

// ---------------- fused MFMA GEMM + LSTM cell (round-6 proven) ----------------
// Block: 256 threads = 4 waves, tile 64 rows x 256 cols (blockIdx.y = col half).
// kt-major B pack: 4 contiguous-1KB global_load_lds per wave per kt.
// Double-buffered LDS; one __syncthreads per kt carries the vmcnt/lgkm drain.
// __launch_bounds__(256,4): LDS 40KB x 4 = 160KB exact -> 4 blocks/CU.
// FIRST=true: skip all-zero h-state A-part at step 0 and the c_old read.
#define BM 64

template <int PARTS, bool FIRST>
__global__ __launch_bounds__(256, 4) void gemm_lstm(
    const f16* __restrict__ A0, const f16* __restrict__ A1, const f16* __restrict__ A2,
    const f16* __restrict__ Bpk, const float* __restrict__ bp,
    float* __restrict__ c, f16* __restrict__ h_out, int nrows) {
    constexpr int NKT = PARTS * 4;                           // B chunks in pack
    constexpr int NT = FIRST ? (PARTS - 1) * 4 : PARTS * 4;  // kt actually run
    __shared__ f16 As[2][64 * 32];    // 8 KB
    __shared__ f16 Bs[2][256 * 32];   // 32 KB

    const int tid = threadIdx.x;
    const int w = tid >> 6;      // wave 0..3
    const int lane = tid & 63;
    const int dl = lane & 15;
    const int quad = lane >> 4;
    const int row0 = blockIdx.x * BM;
    const int cb = blockIdx.y;   // 0..1

    float4v acc[4][4];  // [row-tile rt][gate q]
#pragma unroll
    for (int q = 0; q < 4; ++q) {
        float b = bp[cb * 256 + w * 64 + q * 16 + dl];
#pragma unroll
        for (int rt = 0; rt < 4; ++rt) {
            acc[rt][q][0] = b; acc[rt][q][1] = b; acc[rt][q][2] = b; acc[rt][q][3] = b;
        }
    }

    const int srow = lane >> 2;       // A staging row within 16-row group
    const int sj = lane & 3;          // A staging slot
    const int sg = sj ^ ((srow >> 1) & 3);            // swizzled global k-group
    const int rslot = (quad ^ ((dl >> 1) & 3)) << 3;  // swizzled read slot (halves)

    // per-lane source base into the kt-major pack (this wave's 4KB share)
    const f16* Bk0 = Bpk + (size_t)cb * NKT * 8192 + w * 2048 + lane * 8;

    auto stage = [&](int kt, int bsel) {
        const f16* Ap = A0;
        const int pi = kt >> 2;
        if (PARTS >= 2 && pi == 1) Ap = A1;
        if (PARTS >= 3 && pi == 2) Ap = A2;
        const int kk = (kt & 3) * 32;   // A-part-local k offset
        async_copy16(&Ap[(size_t)(row0 + w * 16 + srow) * 128 + kk + (sg << 3)],
                     (f16*)As[bsel] + w * 512);
        // B: 4 x contiguous 1KB bursts per wave from the kt-major LDS-image pack
        const f16* Bsrc = Bk0 + (size_t)kt * 8192;
#pragma unroll
        for (int i = 0; i < 4; ++i)
            async_copy16(Bsrc + i * 512, (f16*)Bs[bsel] + w * 2048 + i * 512);
    };

    // prologue: stage tile 0; __syncthreads drains vmcnt(0) for all threads
    stage(0, 0);
    __syncthreads();

    for (int kt = 0; kt < NT; ++kt) {
        const int cur = kt & 1;
        if (kt + 1 < NT) stage(kt + 1, cur ^ 1);   // prefetch overlaps compute

        half8 a[4], b[4];
#pragma unroll
        for (int rt = 0; rt < 4; ++rt)
            a[rt] = *(const half8*)&As[cur][(rt * 16 + dl) * 32 + rslot];
#pragma unroll
        for (int q = 0; q < 4; ++q)
            b[q] = *(const half8*)&Bs[cur][((w * 4 + q) * 16 + dl) * 32 + rslot];
#pragma unroll
        for (int rt = 0; rt < 4; ++rt)
#pragma unroll
            for (int q = 0; q < 4; ++q)
                acc[rt][q] = __builtin_amdgcn_mfma_f32_16x16x32_f16(a[rt], b[q], acc[rt][q], 0, 0, 0);

        __syncthreads();   // drains vmcnt(0)+lgkmcnt(0): prefetch visible, reads done
    }

    // epilogue: lane owns dim d, rows rt*16 + quad*4 + r, gates in acc[rt][*]
    float* cpriv = c + ((size_t)(blockIdx.x * 2 + cb)) * 4096;
    const int d = cb * 64 + w * 16 + dl;
#pragma unroll
    for (int rt = 0; rt < 4; ++rt) {
        float4v ig = acc[rt][0], fg = acc[rt][1], gg = acc[rt][2], og = acc[rt][3];
        float* cp = cpriv + rt * 1024 + tid * 4;
        float4v cold;
        if (FIRST) {
            cold[0] = 0.0f; cold[1] = 0.0f; cold[2] = 0.0f; cold[3] = 0.0f;
        } else {
            cold = *(const float4v*)cp;
        }
        float4v cn;
        float hn[4];
#pragma unroll
        for (int r = 0; r < 4; ++r) {
            float i_ = fast_sigmoid(ig[r]);
            float f_ = fast_sigmoid(fg[r]);
            float g_ = fast_tanh(gg[r]);
            float o_ = fast_sigmoid(og[r]);
            float cv = f_ * cold[r] + i_ * g_;
            cn[r] = cv;
            hn[r] = o_ * fast_tanh(cv);
        }
        *(float4v*)cp = cn;
#pragma unroll
        for (int r = 0; r < 4; ++r) {
            int nr = row0 + rt * 16 + (quad << 2) + r;
            if (nr < nrows) h_out[(size_t)nr * 128 + d] = (f16)hn[r];
        }
    }
}

// ---------------- output projection: 16 nodes/block ----------------
__global__ __launch_bounds__(256, 8) void out_kernel(
    const f16* __restrict__ h2, const float* __restrict__ Wout,
    const float* __restrict__ bout, float* __restrict__ out, int n) {
    int grp = threadIdx.x >> 4;
    int l = threadIdx.x & 15;
    int node = blockIdx.x * 16 + grp;
    if (node >= n) return;
    half8 h = *(const half8*)&h2[(size_t)node * 128 + l * 8];
    float s = 0.0f;
#pragma unroll
    for (int j = 0; j < 8; ++j) s += (float)h[j] * Wout[l * 8 + j];
#pragma unroll
    for (int o = 8; o > 0; o >>= 1) s += __shfl_down(s, o, 16);
    if (l == 0) out[node] = s + bout[0];
}

// ---------------- launch ----------------
extern "C" void kernel_launch(void* const* d_in, const int* in_sizes, int n_in,
                              void* d_out, int out_size, void* d_ws, size_t ws_size,
                              hipStream_t stream) {
    const float* features = (const float*)d_in[0];
    const int*   src      = (const int*)d_in[1];
    const int*   dst      = (const int*)d_in[2];
    const float* W_in     = (const float*)d_in[3];
    const float* b_in     = (const float*)d_in[4];
    const float* Wih0     = (const float*)d_in[5];
    const float* Wih_rest = (const float*)d_in[6];
    const float* Whh      = (const float*)d_in[7];
    const float* bih      = (const float*)d_in[8];
    const float* bhh      = (const float*)d_in[9];
    const float* W_out    = (const float*)d_in[10];
    const float* b_out    = (const float*)d_in[11];
    float* out = (float*)d_out;

    const int N = in_sizes[0] / 6;  // 20000
    const int E = in_sizes[1];      // 640000
    const int NP = N + BM;          // padded rows: staging never reads unmapped mem

    char* ws = (char*)d_ws;
    size_t pos = 0;
    auto alloc = [&](size_t bytes) -> void* {
        void* p = ws + pos;
        pos = (pos + bytes + 255) & ~(size_t)255;
        return p;
    };
    const size_t hrow = 128;
    const size_t hbytes = (size_t)NP * hrow * sizeof(f16);
    const size_t cbytes = (size_t)NP * hrow * sizeof(float);
    f16* feath = (f16*)alloc(hbytes);
    f16* aggh  = (f16*)alloc(hbytes);
    f16* hblk  = (f16*)alloc(6 * hbytes);   // ping-pong: A-set then B-set
    f16* hA[3], * hB[3];
    for (int l = 0; l < 3; ++l) {
        hA[l] = hblk + (size_t)l * NP * hrow;
        hB[l] = hblk + (size_t)(l + 3) * NP * hrow;
    }
    float* cblk = (float*)alloc(3 * cbytes);
    float* c0 = cblk + 0 * (size_t)NP * hrow;   // block-private layout, 626*4096 <= NP*128
    float* c1 = cblk + 1 * (size_t)NP * hrow;
    float* c2 = cblk + 2 * (size_t)NP * hrow;
    f16* Bp0 = (f16*)alloc((size_t)512 * 384 * sizeof(f16));
    f16* Bp1 = (f16*)alloc((size_t)512 * 256 * sizeof(f16));
    f16* Bp2 = (f16*)alloc((size_t)512 * 256 * sizeof(f16));
    float* bp0 = (float*)alloc(512 * sizeof(float));
    float* bp1 = (float*)alloc(512 * sizeof(float));
    float* bp2 = (float*)alloc(512 * sizeof(float));
    int*   cnt   = (int*)alloc((size_t)N * 4);
    int*   offs  = (int*)alloc((size_t)(N + 1) * 4);
    int*   cur   = (int*)alloc((size_t)N * 4);
    int*   esrc  = (int*)alloc((size_t)E * 4);
    float* recip = (float*)alloc((size_t)N * 4);
    int*   dh    = (int*)alloc(128 * 4);
    int*   perm  = (int*)alloc((size_t)N * 4);

    hipMemsetAsync(cnt, 0, (size_t)N * 4, stream);
    hipMemsetAsync(dh, 0, 128 * 4, stream);
    hipMemsetAsync(feath + (size_t)N * hrow, 0, (size_t)(NP - N) * hrow * sizeof(f16), stream);
    hipMemsetAsync(aggh + (size_t)N * hrow, 0, (size_t)(NP - N) * hrow * sizeof(f16), stream);

    // kt-major packs: L0 NKT=12, L1/L2 NKT=8
    packb_kernel<<<(512 * 384 + 255) / 256, 256, 0, stream>>>(
        Wih0, 256, Whh, 384, 12, bih, bhh, Bp0, bp0);
    packb_kernel<<<(512 * 256 + 255) / 256, 256, 0, stream>>>(
        Wih_rest, 128, Whh + 512 * 128, 256, 8, bih + 512, bhh + 512, Bp1, bp1);
    packb_kernel<<<(512 * 256 + 255) / 256, 256, 0, stream>>>(
        Wih_rest + 512 * 128, 128, Whh + 2 * 512 * 128, 256, 8, bih + 1024, bhh + 1024, Bp2, bp2);

    feat0_kernel<<<(N * 128 + 255) / 256, 256, 0, stream>>>(features, W_in, b_in, feath, N);
    hist_kernel<<<(E + 255) / 256, 256, 0, stream>>>(dst, cnt, E);
    scan_kernel<<<1, 1024, 0, stream>>>(cnt, offs, cur, recip, N);
    // degree-sort permutation (counting sort over 128 bins)
    dhist_kernel<<<(N + 255) / 256, 256, 0, stream>>>(cnt, dh, N);
    dscan_kernel<<<1, 128, 0, stream>>>(dh, dh);   // in-place: bins -> cursors
    dperm_kernel<<<(N + 255) / 256, 256, 0, stream>>>(cnt, dh, perm, N);
    scatter_kernel<<<(E + 255) / 256, 256, 0, stream>>>(src, dst, cur, esrc, E);

    const dim3 ggrid((N + BM - 1) / BM, 2, 1);
    const int gagg = (N + 15) / 16;
    const f16* featcur = feath;
    f16 *r0 = hA[0], *r1 = hA[1], *r2 = hA[2];   // read (old state)
    f16 *w0 = hB[0], *w1 = hB[1], *w2 = hB[2];   // write (new state)
    for (int step = 0; step < 11; ++step) {
        agg_kernel<<<gagg, 256, 0, stream>>>(featcur, offs, esrc, recip, perm, aggh, N);
        if (step == 0) {
            gemm_lstm<3, true ><<<ggrid, 256, 0, stream>>>(aggh, featcur, r0, Bp0, bp0, c0, w0, N);
            gemm_lstm<2, true ><<<ggrid, 256, 0, stream>>>(w0, r1, nullptr, Bp1, bp1, c1, w1, N);
            gemm_lstm<2, true ><<<ggrid, 256, 0, stream>>>(w1, r2, nullptr, Bp2, bp2, c2, w2, N);
        } else {
            gemm_lstm<3, false><<<ggrid, 256, 0, stream>>>(aggh, featcur, r0, Bp0, bp0, c0, w0, N);
            gemm_lstm<2, false><<<ggrid, 256, 0, stream>>>(w0, r1, nullptr, Bp1, bp1, c1, w1, N);
            gemm_lstm<2, false><<<ggrid, 256, 0, stream>>>(w1, r2, nullptr, Bp2, bp2, c2, w2, N);
        }
        featcur = w2;
        f16* t;
        t = r0; r0 = w0; w0 = t;
        t = r1; r1 = w1; w1 = t;
        t = r2; r2 = w2; w2 = t;
    }
    out_kernel<<<(N + 15) / 16, 256, 0, stream>>>((const f16*)featcur, W_out, b_out, out, N);
}

// Round 9
// 1050.741 us; speedup vs baseline: 1.0898x; 1.0415x over previous
//
#include <hip/hip_runtime.h>
#include <math.h>

typedef _Float16 f16;
typedef __attribute__((ext_vector_type(8))) _Float16 half8;
typedef __attribute__((ext_vector_type(4))) _Float16 half4;
typedef __attribute__((ext_vector_type(4))) float float4v;

// ---------------- helpers ----------------
__device__ __forceinline__ float fast_sigmoid(float x) { return 1.0f / (1.0f + __expf(-x)); }
__device__ __forceinline__ float fast_tanh(float x) {
    float a = fabsf(x);
    float e = __expf(-2.0f * a);
    float t = (1.0f - e) / (1.0f + e);
    return copysignf(t, x);
}

// async global->LDS, 16B per lane (64 lanes = 1KB per instruction).
// LDS dest = wave-uniform base + lane*16; global src is per-lane.
__device__ __forceinline__ void async_copy16(const void* gsrc, void* ldst) {
    __builtin_amdgcn_global_load_lds(
        (const __attribute__((address_space(1))) void*)gsrc,
        (__attribute__((address_space(3))) void*)ldst,
        16, 0, 0);
}

// ---------------- prep kernels ----------------
// kt-major, LDS-image B pack: Bpk[cb][kt][colp][sj][e] (f16), 16KB per (cb,kt).
// Element = W[col'][ kt*32 + ((sj ^ ((colp>>1)&3))<<3) + e ], col' = cb*256+colp
// (gate-permuted col' -> j). Staging reads contiguous 1KB bursts.
__global__ void packb_kernel(const float* __restrict__ Wih, int Kih,
                             const float* __restrict__ Whh, int K, int NKT,
                             const float* __restrict__ bih, const float* __restrict__ bhh,
                             f16* __restrict__ Bpk, float* __restrict__ bp) {
    int t = blockIdx.x * blockDim.x + threadIdx.x;
    if (t >= (K << 9)) return;        // 512*K elements total
    int e = t & 7;
    int sj = (t >> 3) & 3;
    int colp = (t >> 5) & 255;
    int rest = t >> 13;
    int kt = rest % NKT;
    int cb = rest / NKT;
    int swz = (colp >> 1) & 3;
    int k = kt * 32 + ((sj ^ swz) << 3) + e;
    int colq = cb * 256 + colp;
    int dg = colq >> 6, q = (colq >> 4) & 3, dl = colq & 15;
    int j = q * 128 + dg * 16 + dl;
    float v = (k < Kih) ? Wih[j * Kih + k] : Whh[j * (K - Kih) + (k - Kih)];
    Bpk[t] = (f16)v;
    if (kt == 0 && e == 0 && sj == swz) bp[colq] = bih[j] + bhh[j];
}

__global__ void feat0_kernel(const float* __restrict__ features, const float* __restrict__ W_in,
                             const float* __restrict__ b_in, f16* __restrict__ feat, int n) {
    int t = blockIdx.x * blockDim.x + threadIdx.x;
    if (t >= n * 128) return;
    int node = t >> 7;
    int d = t & 127;
    float s = b_in[d];
#pragma unroll
    for (int k = 0; k < 6; ++k) s += features[node * 6 + k] * W_in[k * 128 + d];
    feat[t] = (f16)fmaxf(s, 0.0f);
}

__global__ void hist_kernel(const int* __restrict__ dst, int* __restrict__ cnt, int e) {
    int t = blockIdx.x * blockDim.x + threadIdx.x;
    if (t < e) atomicAdd(&cnt[dst[t]], 1);
}

// single-block scan, coalesced
__global__ void scan_kernel(const int* __restrict__ cnt, int* __restrict__ off,
                            int* __restrict__ cur, float* __restrict__ recip, int n) {
    __shared__ int wsum[16];
    __shared__ int stot;
    int t = threadIdx.x;       // 1024
    int lane = t & 63, wv = t >> 6;
    int R = 0;
    int rounds = (n + 1023) >> 10;
    for (int i = 0; i < rounds; ++i) {
        int idx = (i << 10) + t;
        int v = (idx < n) ? cnt[idx] : 0;
        int s = v;
#pragma unroll
        for (int o = 1; o < 64; o <<= 1) {
            int u = __shfl_up(s, o, 64);
            if (lane >= o) s += u;
        }
        if (lane == 63) wsum[wv] = s;
        __syncthreads();
        if (t == 0) {
            int a = 0;
#pragma unroll
            for (int j = 0; j < 16; ++j) { int x = wsum[j]; wsum[j] = a; a += x; }
            stot = a;
        }
        __syncthreads();
        int excl = R + wsum[wv] + s - v;
        if (idx < n) {
            off[idx] = excl; cur[idx] = excl;
            recip[idx] = (v > 0) ? 1.0f / (float)v : 0.0f;
        }
        R += stot;
        __syncthreads();
    }
    if (t == 0) off[n] = R;
}

__global__ void scatter_kernel(const int* __restrict__ src, const int* __restrict__ dst,
                               int* __restrict__ cur, int* __restrict__ esrc, int e) {
    int t = blockIdx.x * blockDim.x + threadIdx.x;
    if (t >= e) return;
    int d = dst[t];
    int p = atomicAdd(&cur[d], 1);
    esrc[p] = src[t];
}

// mean aggregation, dim-split for full occupancy:
// block (bx) handles 16 nodes x 64 dims (half h = bx&1); 16 lanes/node x 4 f16.
// 2500 blocks x 4 waves = 10000 waves -> 32 waves/CU (capacity-clamped), +64%
// memory-level parallelism vs the 128-dim version (19.5 waves/CU) for the
// latency-bound gather. Per-edge HBM line count unchanged (2+2 x 64B lines).
// Blocks bx, bx^1 share the same esrc range adjacently in dispatch order.
__global__ __launch_bounds__(256, 8) void agg_kernel(
    const f16* __restrict__ feat, const int* __restrict__ off,
    const int* __restrict__ esrc, const float* __restrict__ recip,
    f16* __restrict__ agg, int n) {
    int slot = threadIdx.x >> 4;
    int l16 = threadIdx.x & 15;
    int bx = blockIdx.x;
    int v = (bx >> 1) * 16 + slot;
    if (v >= n) return;
    const int h = (bx & 1) * 64;
    const f16* fb = feat + h + l16 * 4;
    int e0 = off[v], e1 = off[v + 1];
    float a[4];
#pragma unroll
    for (int j = 0; j < 4; ++j) a[j] = 0.0f;
    int e = e0;
    for (; e + 8 <= e1; e += 8) {
        int ss[8];
#pragma unroll
        for (int u = 0; u < 8; ++u) ss[u] = esrc[e + u];
        half4 vv[8];
#pragma unroll
        for (int u = 0; u < 8; ++u)
            vv[u] = *(const half4*)&fb[(size_t)ss[u] * 128];
#pragma unroll
        for (int u = 0; u < 8; ++u)
#pragma unroll
            for (int j = 0; j < 4; ++j) a[j] += (float)vv[u][j];
    }
    for (; e < e1; ++e) {
        half4 v0 = *(const half4*)&fb[(size_t)esrc[e] * 128];
#pragma unroll
        for (int j = 0; j < 4; ++j) a[j] += (float)v0[j];
    }
    float r = recip[v];
    half4 o;
#pragma unroll
    for (int j = 0; j < 4; ++j) o[j] = (f16)(a[j] * r);
    *(half4*)&agg[(size_t)v * 128 + h + l16 * 4] = o;
}

// ---------------- fused MFMA GEMM + LSTM cell (round-6 proven) ----------------
// Block: 256 threads = 4 waves, tile 64 rows x 256 cols (blockIdx.y = col half).
// kt-major B pack: 4 contiguous-1KB global_load_lds per wave per kt.
// Double-buffered LDS; one __syncthreads per kt carries the vmcnt/lgkm drain.
// __launch_bounds__(256,4): LDS 40KB x 4 = 160KB exact -> 4 blocks/CU.
// FIRST=true: skip all-zero h-state A-part at step 0 and the c_old read.
#define BM 64

template <int PARTS, bool FIRST>
__global__ __launch_bounds__(256, 4) void gemm_lstm(
    const f16* __restrict__ A0, const f16* __restrict__ A1, const f16* __restrict__ A2,
    const f16* __restrict__ Bpk, const float* __restrict__ bp,
    float* __restrict__ c, f16* __restrict__ h_out, int nrows) {
    constexpr int NKT = PARTS * 4;                           // B chunks in pack
    constexpr int NT = FIRST ? (PARTS - 1) * 4 : PARTS * 4;  // kt actually run
    __shared__ f16 As[2][64 * 32];    // 8 KB
    __shared__ f16 Bs[2][256 * 32];   // 32 KB

    const int tid = threadIdx.x;
    const int w = tid >> 6;      // wave 0..3
    const int lane = tid & 63;
    const int dl = lane & 15;
    const int quad = lane >> 4;
    const int row0 = blockIdx.x * BM;
    const int cb = blockIdx.y;   // 0..1

    float4v acc[4][4];  // [row-tile rt][gate q]
#pragma unroll
    for (int q = 0; q < 4; ++q) {
        float b = bp[cb * 256 + w * 64 + q * 16 + dl];
#pragma unroll
        for (int rt = 0; rt < 4; ++rt) {
            acc[rt][q][0] = b; acc[rt][q][1] = b; acc[rt][q][2] = b; acc[rt][q][3] = b;
        }
    }

    const int srow = lane >> 2;       // A staging row within 16-row group
    const int sj = lane & 3;          // A staging slot
    const int sg = sj ^ ((srow >> 1) & 3);            // swizzled global k-group
    const int rslot = (quad ^ ((dl >> 1) & 3)) << 3;  // swizzled read slot (halves)

    // per-lane source base into the kt-major pack (this wave's 4KB share)
    const f16* Bk0 = Bpk + (size_t)cb * NKT * 8192 + w * 2048 + lane * 8;

    auto stage = [&](int kt, int bsel) {
        const f16* Ap = A0;
        const int pi = kt >> 2;
        if (PARTS >= 2 && pi == 1) Ap = A1;
        if (PARTS >= 3 && pi == 2) Ap = A2;
        const int kk = (kt & 3) * 32;   // A-part-local k offset
        async_copy16(&Ap[(size_t)(row0 + w * 16 + srow) * 128 + kk + (sg << 3)],
                     (f16*)As[bsel] + w * 512);
        // B: 4 x contiguous 1KB bursts per wave from the kt-major LDS-image pack
        const f16* Bsrc = Bk0 + (size_t)kt * 8192;
#pragma unroll
        for (int i = 0; i < 4; ++i)
            async_copy16(Bsrc + i * 512, (f16*)Bs[bsel] + w * 2048 + i * 512);
    };

    // prologue: stage tile 0; __syncthreads drains vmcnt(0) for all threads
    stage(0, 0);
    __syncthreads();

    for (int kt = 0; kt < NT; ++kt) {
        const int cur = kt & 1;
        if (kt + 1 < NT) stage(kt + 1, cur ^ 1);   // prefetch overlaps compute

        half8 a[4], b[4];
#pragma unroll
        for (int rt = 0; rt < 4; ++rt)
            a[rt] = *(const half8*)&As[cur][(rt * 16 + dl) * 32 + rslot];
#pragma unroll
        for (int q = 0; q < 4; ++q)
            b[q] = *(const half8*)&Bs[cur][((w * 4 + q) * 16 + dl) * 32 + rslot];
#pragma unroll
        for (int rt = 0; rt < 4; ++rt)
#pragma unroll
            for (int q = 0; q < 4; ++q)
                acc[rt][q] = __builtin_amdgcn_mfma_f32_16x16x32_f16(a[rt], b[q], acc[rt][q], 0, 0, 0);

        __syncthreads();   // drains vmcnt(0)+lgkmcnt(0): prefetch visible, reads done
    }

    // epilogue: lane owns dim d, rows rt*16 + quad*4 + r, gates in acc[rt][*]
    float* cpriv = c + ((size_t)(blockIdx.x * 2 + cb)) * 4096;
    const int d = cb * 64 + w * 16 + dl;
#pragma unroll
    for (int rt = 0; rt < 4; ++rt) {
        float4v ig = acc[rt][0], fg = acc[rt][1], gg = acc[rt][2], og = acc[rt][3];
        float* cp = cpriv + rt * 1024 + tid * 4;
        float4v cold;
        if (FIRST) {
            cold[0] = 0.0f; cold[1] = 0.0f; cold[2] = 0.0f; cold[3] = 0.0f;
        } else {
            cold = *(const float4v*)cp;
        }
        float4v cn;
        float hn[4];
#pragma unroll
        for (int r = 0; r < 4; ++r) {
            float i_ = fast_sigmoid(ig[r]);
            float f_ = fast_sigmoid(fg[r]);
            float g_ = fast_tanh(gg[r]);
            float o_ = fast_sigmoid(og[r]);
            float cv = f_ * cold[r] + i_ * g_;
            cn[r] = cv;
            hn[r] = o_ * fast_tanh(cv);
        }
        *(float4v*)cp = cn;
#pragma unroll
        for (int r = 0; r < 4; ++r) {
            int nr = row0 + rt * 16 + (quad << 2) + r;
            if (nr < nrows) h_out[(size_t)nr * 128 + d] = (f16)hn[r];
        }
    }
}

// ---------------- output projection: 16 nodes/block ----------------
__global__ __launch_bounds__(256, 8) void out_kernel(
    const f16* __restrict__ h2, const float* __restrict__ Wout,
    const float* __restrict__ bout, float* __restrict__ out, int n) {
    int grp = threadIdx.x >> 4;
    int l = threadIdx.x & 15;
    int node = blockIdx.x * 16 + grp;
    if (node >= n) return;
    half8 h = *(const half8*)&h2[(size_t)node * 128 + l * 8];
    float s = 0.0f;
#pragma unroll
    for (int j = 0; j < 8; ++j) s += (float)h[j] * Wout[l * 8 + j];
#pragma unroll
    for (int o = 8; o > 0; o >>= 1) s += __shfl_down(s, o, 16);
    if (l == 0) out[node] = s + bout[0];
}

// ---------------- launch ----------------
extern "C" void kernel_launch(void* const* d_in, const int* in_sizes, int n_in,
                              void* d_out, int out_size, void* d_ws, size_t ws_size,
                              hipStream_t stream) {
    const float* features = (const float*)d_in[0];
    const int*   src      = (const int*)d_in[1];
    const int*   dst      = (const int*)d_in[2];
    const float* W_in     = (const float*)d_in[3];
    const float* b_in     = (const float*)d_in[4];
    const float* Wih0     = (const float*)d_in[5];
    const float* Wih_rest = (const float*)d_in[6];
    const float* Whh      = (const float*)d_in[7];
    const float* bih      = (const float*)d_in[8];
    const float* bhh      = (const float*)d_in[9];
    const float* W_out    = (const float*)d_in[10];
    const float* b_out    = (const float*)d_in[11];
    float* out = (float*)d_out;

    const int N = in_sizes[0] / 6;  // 20000
    const int E = in_sizes[1];      // 640000
    const int NP = N + BM;          // padded rows: staging never reads unmapped mem

    char* ws = (char*)d_ws;
    size_t pos = 0;
    auto alloc = [&](size_t bytes) -> void* {
        void* p = ws + pos;
        pos = (pos + bytes + 255) & ~(size_t)255;
        return p;
    };
    const size_t hrow = 128;
    const size_t hbytes = (size_t)NP * hrow * sizeof(f16);
    const size_t cbytes = (size_t)NP * hrow * sizeof(float);
    f16* feath = (f16*)alloc(hbytes);
    f16* aggh  = (f16*)alloc(hbytes);
    f16* hblk  = (f16*)alloc(6 * hbytes);   // ping-pong: A-set then B-set
    f16* hA[3], * hB[3];
    for (int l = 0; l < 3; ++l) {
        hA[l] = hblk + (size_t)l * NP * hrow;
        hB[l] = hblk + (size_t)(l + 3) * NP * hrow;
    }
    float* cblk = (float*)alloc(3 * cbytes);
    float* c0 = cblk + 0 * (size_t)NP * hrow;   // block-private layout, 626*4096 <= NP*128
    float* c1 = cblk + 1 * (size_t)NP * hrow;
    float* c2 = cblk + 2 * (size_t)NP * hrow;
    f16* Bp0 = (f16*)alloc((size_t)512 * 384 * sizeof(f16));
    f16* Bp1 = (f16*)alloc((size_t)512 * 256 * sizeof(f16));
    f16* Bp2 = (f16*)alloc((size_t)512 * 256 * sizeof(f16));
    float* bp0 = (float*)alloc(512 * sizeof(float));
    float* bp1 = (float*)alloc(512 * sizeof(float));
    float* bp2 = (float*)alloc(512 * sizeof(float));
    int*   cnt   = (int*)alloc((size_t)N * 4);
    int*   offs  = (int*)alloc((size_t)(N + 1) * 4);
    int*   cur   = (int*)alloc((size_t)N * 4);
    int*   esrc  = (int*)alloc((size_t)E * 4);
    float* recip = (float*)alloc((size_t)N * 4);

    hipMemsetAsync(cnt, 0, (size_t)N * 4, stream);
    hipMemsetAsync(feath + (size_t)N * hrow, 0, (size_t)(NP - N) * hrow * sizeof(f16), stream);
    hipMemsetAsync(aggh + (size_t)N * hrow, 0, (size_t)(NP - N) * hrow * sizeof(f16), stream);

    // kt-major packs: L0 NKT=12, L1/L2 NKT=8
    packb_kernel<<<(512 * 384 + 255) / 256, 256, 0, stream>>>(
        Wih0, 256, Whh, 384, 12, bih, bhh, Bp0, bp0);
    packb_kernel<<<(512 * 256 + 255) / 256, 256, 0, stream>>>(
        Wih_rest, 128, Whh + 512 * 128, 256, 8, bih + 512, bhh + 512, Bp1, bp1);
    packb_kernel<<<(512 * 256 + 255) / 256, 256, 0, stream>>>(
        Wih_rest + 512 * 128, 128, Whh + 2 * 512 * 128, 256, 8, bih + 1024, bhh + 1024, Bp2, bp2);

    feat0_kernel<<<(N * 128 + 255) / 256, 256, 0, stream>>>(features, W_in, b_in, feath, N);
    hist_kernel<<<(E + 255) / 256, 256, 0, stream>>>(dst, cnt, E);
    scan_kernel<<<1, 1024, 0, stream>>>(cnt, offs, cur, recip, N);
    scatter_kernel<<<(E + 255) / 256, 256, 0, stream>>>(src, dst, cur, esrc, E);

    const dim3 ggrid((N + BM - 1) / BM, 2, 1);
    const int gagg = ((N + 15) / 16) * 2;   // dim-split: 2 blocks per 16 nodes
    const f16* featcur = feath;
    f16 *r0 = hA[0], *r1 = hA[1], *r2 = hA[2];   // read (old state)
    f16 *w0 = hB[0], *w1 = hB[1], *w2 = hB[2];   // write (new state)
    for (int step = 0; step < 11; ++step) {
        agg_kernel<<<gagg, 256, 0, stream>>>(featcur, offs, esrc, recip, aggh, N);
        if (step == 0) {
            gemm_lstm<3, true ><<<ggrid, 256, 0, stream>>>(aggh, featcur, r0, Bp0, bp0, c0, w0, N);
            gemm_lstm<2, true ><<<ggrid, 256, 0, stream>>>(w0, r1, nullptr, Bp1, bp1, c1, w1, N);
            gemm_lstm<2, true ><<<ggrid, 256, 0, stream>>>(w1, r2, nullptr, Bp2, bp2, c2, w2, N);
        } else {
            gemm_lstm<3, false><<<ggrid, 256, 0, stream>>>(aggh, featcur, r0, Bp0, bp0, c0, w0, N);
            gemm_lstm<2, false><<<ggrid, 256, 0, stream>>>(w0, r1, nullptr, Bp1, bp1, c1, w1, N);
            gemm_lstm<2, false><<<ggrid, 256, 0, stream>>>(w1, r2, nullptr, Bp2, bp2, c2, w2, N);
        }
        featcur = w2;
        f16* t;
        t = r0; r0 = w0; w0 = t;
        t = r1; r1 = w1; w1 = t;
        t = r2; r2 = w2; w2 = t;
    }
    out_kernel<<<(N + 15) / 16, 256, 0, stream>>>((const f16*)featcur, W_out, b_out, out, N);
}

// Round 10
// 1009.714 us; speedup vs baseline: 1.1341x; 1.0406x over previous
//
#include <hip/hip_runtime.h>
#include <math.h>

typedef _Float16 f16;
typedef __attribute__((ext_vector_type(8))) _Float16 half8;
typedef __attribute__((ext_vector_type(4))) float float4v;

// ---------------- helpers ----------------
__device__ __forceinline__ float fast_sigmoid(float x) { return 1.0f / (1.0f + __expf(-x)); }
__device__ __forceinline__ float fast_tanh(float x) {
    float a = fabsf(x);
    float e = __expf(-2.0f * a);
    float t = (1.0f - e) / (1.0f + e);
    return copysignf(t, x);
}

// async global->LDS, 16B per lane (64 lanes = 1KB per instruction).
// LDS dest = wave-uniform base + lane*16; global src is per-lane.
__device__ __forceinline__ void async_copy16(const void* gsrc, void* ldst) {
    __builtin_amdgcn_global_load_lds(
        (const __attribute__((address_space(1))) void*)gsrc,
        (__attribute__((address_space(3))) void*)ldst,
        16, 0, 0);
}

// ---------------- prep kernels ----------------
// kt-major, LDS-image B pack: Bpk[cb][kt][colp][sj][e] (f16), 16KB per (cb,kt).
// Element = W[col'][ kt*32 + ((sj ^ ((colp>>1)&3))<<3) + e ], col' = cb*256+colp
// (gate-permuted col' -> j). Staging reads contiguous 1KB bursts.
__global__ void packb_kernel(const float* __restrict__ Wih, int Kih,
                             const float* __restrict__ Whh, int K, int NKT,
                             const float* __restrict__ bih, const float* __restrict__ bhh,
                             f16* __restrict__ Bpk, float* __restrict__ bp) {
    int t = blockIdx.x * blockDim.x + threadIdx.x;
    if (t >= (K << 9)) return;        // 512*K elements total
    int e = t & 7;
    int sj = (t >> 3) & 3;
    int colp = (t >> 5) & 255;
    int rest = t >> 13;
    int kt = rest % NKT;
    int cb = rest / NKT;
    int swz = (colp >> 1) & 3;
    int k = kt * 32 + ((sj ^ swz) << 3) + e;
    int colq = cb * 256 + colp;
    int dg = colq >> 6, q = (colq >> 4) & 3, dl = colq & 15;
    int j = q * 128 + dg * 16 + dl;
    float v = (k < Kih) ? Wih[j * Kih + k] : Whh[j * (K - Kih) + (k - Kih)];
    Bpk[t] = (f16)v;
    if (kt == 0 && e == 0 && sj == swz) bp[colq] = bih[j] + bhh[j];
}

__global__ void feat0_kernel(const float* __restrict__ features, const float* __restrict__ W_in,
                             const float* __restrict__ b_in, f16* __restrict__ feat, int n) {
    int t = blockIdx.x * blockDim.x + threadIdx.x;
    if (t >= n * 128) return;
    int node = t >> 7;
    int d = t & 127;
    float s = b_in[d];
#pragma unroll
    for (int k = 0; k < 6; ++k) s += features[node * 6 + k] * W_in[k * 128 + d];
    feat[t] = (f16)fmaxf(s, 0.0f);
}

__global__ void hist_kernel(const int* __restrict__ dst, int* __restrict__ cnt, int e) {
    int t = blockIdx.x * blockDim.x + threadIdx.x;
    if (t < e) atomicAdd(&cnt[dst[t]], 1);
}

// single-block scan, coalesced
__global__ void scan_kernel(const int* __restrict__ cnt, int* __restrict__ off,
                            int* __restrict__ cur, float* __restrict__ recip, int n) {
    __shared__ int wsum[16];
    __shared__ int stot;
    int t = threadIdx.x;       // 1024
    int lane = t & 63, wv = t >> 6;
    int R = 0;
    int rounds = (n + 1023) >> 10;
    for (int i = 0; i < rounds; ++i) {
        int idx = (i << 10) + t;
        int v = (idx < n) ? cnt[idx] : 0;
        int s = v;
#pragma unroll
        for (int o = 1; o < 64; o <<= 1) {
            int u = __shfl_up(s, o, 64);
            if (lane >= o) s += u;
        }
        if (lane == 63) wsum[wv] = s;
        __syncthreads();
        if (t == 0) {
            int a = 0;
#pragma unroll
            for (int j = 0; j < 16; ++j) { int x = wsum[j]; wsum[j] = a; a += x; }
            stot = a;
        }
        __syncthreads();
        int excl = R + wsum[wv] + s - v;
        if (idx < n) {
            off[idx] = excl; cur[idx] = excl;
            recip[idx] = (v > 0) ? 1.0f / (float)v : 0.0f;
        }
        R += stot;
        __syncthreads();
    }
    if (t == 0) off[n] = R;
}

__global__ void scatter_kernel(const int* __restrict__ src, const int* __restrict__ dst,
                               int* __restrict__ cur, int* __restrict__ esrc, int e) {
    int t = blockIdx.x * blockDim.x + threadIdx.x;
    if (t >= e) return;
    int d = dst[t];
    int p = atomicAdd(&cur[d], 1);
    esrc[p] = src[t];
}

// mean aggregation: 16 lanes (8 halves each) per node, 16 nodes/block (proven)
__global__ __launch_bounds__(256, 6) void agg_kernel(
    const f16* __restrict__ feat, const int* __restrict__ off,
    const int* __restrict__ esrc, const float* __restrict__ recip,
    f16* __restrict__ agg, int n) {
    int slot = threadIdx.x >> 4;
    int lane = threadIdx.x & 15;
    int v = blockIdx.x * 16 + slot;
    if (v >= n) return;
    int e0 = off[v], e1 = off[v + 1];
    float a[8];
#pragma unroll
    for (int j = 0; j < 8; ++j) a[j] = 0.0f;
    int e = e0;
    for (; e + 8 <= e1; e += 8) {
        int ss[8];
#pragma unroll
        for (int u = 0; u < 8; ++u) ss[u] = esrc[e + u];
        half8 vv[8];
#pragma unroll
        for (int u = 0; u < 8; ++u)
            vv[u] = *(const half8*)&feat[(size_t)ss[u] * 128 + lane * 8];
#pragma unroll
        for (int u = 0; u < 8; ++u)
#pragma unroll
            for (int j = 0; j < 8; ++j) a[j] += (float)vv[u][j];
    }
    for (; e < e1; ++e) {
        int s = esrc[e];
        half8 v0 = *(const half8*)&feat[(size_t)s * 128 + lane * 8];
#pragma unroll
        for (int j = 0; j < 8; ++j) a[j] += (float)v0[j];
    }
    float r = recip[v];
    half8 o;
#pragma unroll
    for (int j = 0; j < 8; ++j) o[j] = (f16)(a[j] * r);
    *(half8*)&agg[(size_t)v * 128 + lane * 8] = o;
}

// ---------------- fused MFMA GEMM + LSTM cell (round-6 proven) ----------------
// Block: 256 threads = 4 waves, tile 64 rows x 256 cols (blockIdx.y = col half).
// kt-major B pack: 4 contiguous-1KB global_load_lds per wave per kt.
// Double-buffered LDS; one __syncthreads per kt carries the vmcnt/lgkm drain.
// __launch_bounds__(256,4): LDS 40KB x 4 = 160KB exact -> 4 blocks/CU.
// FIRST=true: skip all-zero h-state A-part at step 0 and the c_old read.
#define BM 64

template <int PARTS, bool FIRST>
__global__ __launch_bounds__(256, 4) void gemm_lstm(
    const f16* __restrict__ A0, const f16* __restrict__ A1, const f16* __restrict__ A2,
    const f16* __restrict__ Bpk, const float* __restrict__ bp,
    float* __restrict__ c, f16* __restrict__ h_out, int nrows) {
    constexpr int NKT = PARTS * 4;                           // B chunks in pack
    constexpr int NT = FIRST ? (PARTS - 1) * 4 : PARTS * 4;  // kt actually run
    __shared__ f16 As[2][64 * 32];    // 8 KB
    __shared__ f16 Bs[2][256 * 32];   // 32 KB

    const int tid = threadIdx.x;
    const int w = tid >> 6;      // wave 0..3
    const int lane = tid & 63;
    const int dl = lane & 15;
    const int quad = lane >> 4;
    const int row0 = blockIdx.x * BM;
    const int cb = blockIdx.y;   // 0..1

    float4v acc[4][4];  // [row-tile rt][gate q]
#pragma unroll
    for (int q = 0; q < 4; ++q) {
        float b = bp[cb * 256 + w * 64 + q * 16 + dl];
#pragma unroll
        for (int rt = 0; rt < 4; ++rt) {
            acc[rt][q][0] = b; acc[rt][q][1] = b; acc[rt][q][2] = b; acc[rt][q][3] = b;
        }
    }

    const int srow = lane >> 2;       // A staging row within 16-row group
    const int sj = lane & 3;          // A staging slot
    const int sg = sj ^ ((srow >> 1) & 3);            // swizzled global k-group
    const int rslot = (quad ^ ((dl >> 1) & 3)) << 3;  // swizzled read slot (halves)

    // per-lane source base into the kt-major pack (this wave's 4KB share)
    const f16* Bk0 = Bpk + (size_t)cb * NKT * 8192 + w * 2048 + lane * 8;

    auto stage = [&](int kt, int bsel) {
        const f16* Ap = A0;
        const int pi = kt >> 2;
        if (PARTS >= 2 && pi == 1) Ap = A1;
        if (PARTS >= 3 && pi == 2) Ap = A2;
        const int kk = (kt & 3) * 32;   // A-part-local k offset
        async_copy16(&Ap[(size_t)(row0 + w * 16 + srow) * 128 + kk + (sg << 3)],
                     (f16*)As[bsel] + w * 512);
        // B: 4 x contiguous 1KB bursts per wave from the kt-major LDS-image pack
        const f16* Bsrc = Bk0 + (size_t)kt * 8192;
#pragma unroll
        for (int i = 0; i < 4; ++i)
            async_copy16(Bsrc + i * 512, (f16*)Bs[bsel] + w * 2048 + i * 512);
    };

    // prologue: stage tile 0; __syncthreads drains vmcnt(0) for all threads
    stage(0, 0);
    __syncthreads();

    for (int kt = 0; kt < NT; ++kt) {
        const int cur = kt & 1;
        if (kt + 1 < NT) stage(kt + 1, cur ^ 1);   // prefetch overlaps compute

        half8 a[4], b[4];
#pragma unroll
        for (int rt = 0; rt < 4; ++rt)
            a[rt] = *(const half8*)&As[cur][(rt * 16 + dl) * 32 + rslot];
#pragma unroll
        for (int q = 0; q < 4; ++q)
            b[q] = *(const half8*)&Bs[cur][((w * 4 + q) * 16 + dl) * 32 + rslot];
#pragma unroll
        for (int rt = 0; rt < 4; ++rt)
#pragma unroll
            for (int q = 0; q < 4; ++q)
                acc[rt][q] = __builtin_amdgcn_mfma_f32_16x16x32_f16(a[rt], b[q], acc[rt][q], 0, 0, 0);

        __syncthreads();   // drains vmcnt(0)+lgkmcnt(0): prefetch visible, reads done
    }

    // epilogue: lane owns dim d, rows rt*16 + quad*4 + r, gates in acc[rt][*]
    float* cpriv = c + ((size_t)(blockIdx.x * 2 + cb)) * 4096;
    const int d = cb * 64 + w * 16 + dl;
#pragma unroll
    for (int rt = 0; rt < 4; ++rt) {
        float4v ig = acc[rt][0], fg = acc[rt][1], gg = acc[rt][2], og = acc[rt][3];
        float* cp = cpriv + rt * 1024 + tid * 4;
        float4v cold;
        if (FIRST) {
            cold[0] = 0.0f; cold[1] = 0.0f; cold[2] = 0.0f; cold[3] = 0.0f;
        } else {
            cold = *(const float4v*)cp;
        }
        float4v cn;
        float hn[4];
#pragma unroll
        for (int r = 0; r < 4; ++r) {
            float i_ = fast_sigmoid(ig[r]);
            float f_ = fast_sigmoid(fg[r]);
            float g_ = fast_tanh(gg[r]);
            float o_ = fast_sigmoid(og[r]);
            float cv = f_ * cold[r] + i_ * g_;
            cn[r] = cv;
            hn[r] = o_ * fast_tanh(cv);
        }
        *(float4v*)cp = cn;
#pragma unroll
        for (int r = 0; r < 4; ++r) {
            int nr = row0 + rt * 16 + (quad << 2) + r;
            if (nr < nrows) h_out[(size_t)nr * 128 + d] = (f16)hn[r];
        }
    }
}

// ---------------- output projection: 16 nodes/block ----------------
__global__ __launch_bounds__(256, 8) void out_kernel(
    const f16* __restrict__ h2, const float* __restrict__ Wout,
    const float* __restrict__ bout, float* __restrict__ out, int n) {
    int grp = threadIdx.x >> 4;
    int l = threadIdx.x & 15;
    int node = blockIdx.x * 16 + grp;
    if (node >= n) return;
    half8 h = *(const half8*)&h2[(size_t)node * 128 + l * 8];
    float s = 0.0f;
#pragma unroll
    for (int j = 0; j < 8; ++j) s += (float)h[j] * Wout[l * 8 + j];
#pragma unroll
    for (int o = 8; o > 0; o >>= 1) s += __shfl_down(s, o, 16);
    if (l == 0) out[node] = s + bout[0];
}

// ---------------- launch ----------------
extern "C" void kernel_launch(void* const* d_in, const int* in_sizes, int n_in,
                              void* d_out, int out_size, void* d_ws, size_t ws_size,
                              hipStream_t stream) {
    const float* features = (const float*)d_in[0];
    const int*   src      = (const int*)d_in[1];
    const int*   dst      = (const int*)d_in[2];
    const float* W_in     = (const float*)d_in[3];
    const float* b_in     = (const float*)d_in[4];
    const float* Wih0     = (const float*)d_in[5];
    const float* Wih_rest = (const float*)d_in[6];
    const float* Whh      = (const float*)d_in[7];
    const float* bih      = (const float*)d_in[8];
    const float* bhh      = (const float*)d_in[9];
    const float* W_out    = (const float*)d_in[10];
    const float* b_out    = (const float*)d_in[11];
    float* out = (float*)d_out;

    const int N = in_sizes[0] / 6;  // 20000
    const int E = in_sizes[1];      // 640000
    const int NP = N + BM;          // padded rows: staging never reads unmapped mem

    char* ws = (char*)d_ws;
    size_t pos = 0;
    auto alloc = [&](size_t bytes) -> void* {
        void* p = ws + pos;
        pos = (pos + bytes + 255) & ~(size_t)255;
        return p;
    };
    const size_t hrow = 128;
    const size_t hbytes = (size_t)NP * hrow * sizeof(f16);
    const size_t cbytes = (size_t)NP * hrow * sizeof(float);
    f16* feath = (f16*)alloc(hbytes);
    f16* aggh  = (f16*)alloc(hbytes);
    f16* hblk  = (f16*)alloc(6 * hbytes);   // ping-pong: A-set then B-set
    f16* hA[3], * hB[3];
    for (int l = 0; l < 3; ++l) {
        hA[l] = hblk + (size_t)l * NP * hrow;
        hB[l] = hblk + (size_t)(l + 3) * NP * hrow;
    }
    float* cblk = (float*)alloc(3 * cbytes);
    float* c0 = cblk + 0 * (size_t)NP * hrow;   // block-private layout, 626*4096 <= NP*128
    float* c1 = cblk + 1 * (size_t)NP * hrow;
    float* c2 = cblk + 2 * (size_t)NP * hrow;
    f16* Bp0 = (f16*)alloc((size_t)512 * 384 * sizeof(f16));
    f16* Bp1 = (f16*)alloc((size_t)512 * 256 * sizeof(f16));
    f16* Bp2 = (f16*)alloc((size_t)512 * 256 * sizeof(f16));
    float* bp0 = (float*)alloc(512 * sizeof(float));
    float* bp1 = (float*)alloc(512 * sizeof(float));
    float* bp2 = (float*)alloc(512 * sizeof(float));
    int*   cnt   = (int*)alloc((size_t)N * 4);
    int*   offs  = (int*)alloc((size_t)(N + 1) * 4);
    int*   cur   = (int*)alloc((size_t)N * 4);
    int*   esrc  = (int*)alloc((size_t)E * 4);
    float* recip = (float*)alloc((size_t)N * 4);

    hipMemsetAsync(cnt, 0, (size_t)N * 4, stream);
    hipMemsetAsync(feath + (size_t)N * hrow, 0, (size_t)(NP - N) * hrow * sizeof(f16), stream);
    hipMemsetAsync(aggh + (size_t)N * hrow, 0, (size_t)(NP - N) * hrow * sizeof(f16), stream);

    // kt-major packs: L0 NKT=12, L1/L2 NKT=8
    packb_kernel<<<(512 * 384 + 255) / 256, 256, 0, stream>>>(
        Wih0, 256, Whh, 384, 12, bih, bhh, Bp0, bp0);
    packb_kernel<<<(512 * 256 + 255) / 256, 256, 0, stream>>>(
        Wih_rest, 128, Whh + 512 * 128, 256, 8, bih + 512, bhh + 512, Bp1, bp1);
    packb_kernel<<<(512 * 256 + 255) / 256, 256, 0, stream>>>(
        Wih_rest + 512 * 128, 128, Whh + 2 * 512 * 128, 256, 8, bih + 1024, bhh + 1024, Bp2, bp2);

    feat0_kernel<<<(N * 128 + 255) / 256, 256, 0, stream>>>(features, W_in, b_in, feath, N);
    hist_kernel<<<(E + 255) / 256, 256, 0, stream>>>(dst, cnt, E);
    scan_kernel<<<1, 1024, 0, stream>>>(cnt, offs, cur, recip, N);
    scatter_kernel<<<(E + 255) / 256, 256, 0, stream>>>(src, dst, cur, esrc, E);

    const dim3 ggrid((N + BM - 1) / BM, 2, 1);
    const int gagg = (N + 15) / 16;
    const f16* featcur = feath;
    f16 *r0 = hA[0], *r1 = hA[1], *r2 = hA[2];   // read (old state)
    f16 *w0 = hB[0], *w1 = hB[1], *w2 = hB[2];   // write (new state)
    for (int step = 0; step < 11; ++step) {
        agg_kernel<<<gagg, 256, 0, stream>>>(featcur, offs, esrc, recip, aggh, N);
        if (step == 0) {
            gemm_lstm<3, true ><<<ggrid, 256, 0, stream>>>(aggh, featcur, r0, Bp0, bp0, c0, w0, N);
            gemm_lstm<2, true ><<<ggrid, 256, 0, stream>>>(w0, r1, nullptr, Bp1, bp1, c1, w1, N);
            gemm_lstm<2, true ><<<ggrid, 256, 0, stream>>>(w1, r2, nullptr, Bp2, bp2, c2, w2, N);
        } else {
            gemm_lstm<3, false><<<ggrid, 256, 0, stream>>>(aggh, featcur, r0, Bp0, bp0, c0, w0, N);
            gemm_lstm<2, false><<<ggrid, 256, 0, stream>>>(w0, r1, nullptr, Bp1, bp1, c1, w1, N);
            gemm_lstm<2, false><<<ggrid, 256, 0, stream>>>(w1, r2, nullptr, Bp2, bp2, c2, w2, N);
        }
        featcur = w2;
        f16* t;
        t = r0; r0 = w0; w0 = t;
        t = r1; r1 = w1; w1 = t;
        t = r2; r2 = w2; w2 = t;
    }
    out_kernel<<<(N + 15) / 16, 256, 0, stream>>>((const f16*)featcur, W_out, b_out, out, N);
}